// Round 4
// baseline (699.508 us; speedup 1.0000x reference)
//
#include <hip/hip_runtime.h>
#include <hip/hip_bf16.h>
#include <stdint.h>

#define ZD 128
#define SD 512
#define MROWS (SD*SD)   // 262144 rows

typedef __attribute__((ext_vector_type(8))) short short8;
typedef __attribute__((ext_vector_type(4))) float floatx4;
typedef __attribute__((ext_vector_type(4))) unsigned short ushort4v;

__device__ __forceinline__ unsigned short f2bf(float f) {
  union { float f; unsigned u; } c; c.f = f;
  unsigned r = c.u + 0x7FFFu + ((c.u >> 16) & 1u);   // RNE
  return (unsigned short)(r >> 16);
}
__device__ __forceinline__ float bf2f(unsigned short h) {
  union { unsigned u; float f; } c; c.u = (unsigned)h << 16;
  return c.f;
}
__device__ __forceinline__ float sigm(float x) { return 1.0f / (1.0f + __expf(-x)); }

// swizzled LDS byte offset for 256B rows
#define SWZ(r, cb) (((r) << 8) + ((cb) ^ (((r) & 7) << 4)))
// swizzled LDS byte offset for 128B rows
#define SWZ64(r, cb) (((r) << 7) + ((cb) ^ (((r) & 7) << 4)))

// ---------------------------------------------------------------- prep: bf16+transpose weights
__global__ __launch_bounds__(256) void prep_weights(
    const float* __restrict__ l1, const float* __restrict__ l2,
    const float* __restrict__ r1, const float* __restrict__ r2,
    const float* __restrict__ gw, const float* __restrict__ ow,
    unsigned short* __restrict__ dst) {
  const float* srcs[6] = {l1, l2, r1, r2, gw, ow};
  const float* s = srcs[blockIdx.x];
  unsigned short* d = dst + (size_t)blockIdx.x * ZD * ZD;
  for (int i = threadIdx.x; i < ZD * ZD; i += blockDim.x) {
    int k = i >> 7, n = i & 127;
    d[n * ZD + k] = f2bf(s[i]);     // WT[n][k] = W[k][n]
  }
}

// ---------------------------------------------------------------- LN over Z, f32 -> bf16 x
__global__ __launch_bounds__(256) void ln_kernel(
    const float* __restrict__ in, const float* __restrict__ w,
    const float* __restrict__ b, unsigned short* __restrict__ xo) {
  const int tid = threadIdx.x;
  const int lane = tid & 63;
  const int row = blockIdx.x * 4 + (tid >> 6);
  float2 v = reinterpret_cast<const float2*>(in)[(size_t)row * 64 + lane];
  float s = v.x + v.y, q = v.x * v.x + v.y * v.y;
  #pragma unroll
  for (int m = 1; m < 64; m <<= 1) { s += __shfl_xor(s, m); q += __shfl_xor(q, m); }
  float mu = s * (1.0f / ZD);
  float var = q * (1.0f / ZD) - mu * mu;
  float rstd = rsqrtf(var + 1e-5f);
  float2 wv = reinterpret_cast<const float2*>(w)[lane];
  float2 bv = reinterpret_cast<const float2*>(b)[lane];
  unsigned o0 = f2bf((v.x - mu) * rstd * wv.x + bv.x);
  unsigned o1 = f2bf((v.y - mu) * rstd * wv.y + bv.y);
  reinterpret_cast<unsigned*>(xo)[(size_t)row * 64 + lane] = o0 | (o1 << 16);
}

// ---------------------------------------------------------------- fused projections, M-tile 64
// low-VGPR: per wave 32x64 output per job, acc[2][4]x2 = 64 regs
template<bool TWO>
__device__ __forceinline__ void proj_job(
    const char* xs, const unsigned short* __restrict__ w1,
    const unsigned short* __restrict__ w2, unsigned short* __restrict__ dst,
    int m0, int msub, int esub, int fr, int fq) {
  floatx4 acc1[2][4] = {};
  floatx4 acc2[2][4] = {};
  #pragma unroll
  for (int ks = 0; ks < 4; ++ks) {
    const int kb = ks * 64 + fq * 16;     // byte offset within LDS row
    const int kw = ks * 32 + fq * 8;      // short offset within weight row
    short8 a[2];
    #pragma unroll
    for (int i = 0; i < 2; ++i)
      a[i] = *reinterpret_cast<const short8*>(xs + SWZ(msub + i * 16 + fr, kb));
    #pragma unroll
    for (int j = 0; j < 4; ++j) {
      const int erow = esub + j * 16 + fr;
      short8 b1 = *reinterpret_cast<const short8*>(w1 + (size_t)erow * ZD + kw);
      #pragma unroll
      for (int i = 0; i < 2; ++i)
        acc1[i][j] = __builtin_amdgcn_mfma_f32_16x16x32_bf16(a[i], b1, acc1[i][j], 0, 0, 0);
      if (TWO) {
        short8 b2 = *reinterpret_cast<const short8*>(w2 + (size_t)erow * ZD + kw);
        #pragma unroll
        for (int i = 0; i < 2; ++i)
          acc2[i][j] = __builtin_amdgcn_mfma_f32_16x16x32_bf16(a[i], b2, acc2[i][j], 0, 0, 0);
      }
    }
  }
  #pragma unroll
  for (int i = 0; i < 2; ++i) {
    const int mrow = m0 + msub + i * 16 + fq * 4;     // 4 reg-consecutive rows
    #pragma unroll
    for (int j = 0; j < 4; ++j) {
      const int e = esub + j * 16 + fr;
      ushort4v pkt;
      #pragma unroll
      for (int r = 0; r < 4; ++r) {
        float v = TWO ? sigm(acc1[i][j][r]) * acc2[i][j][r] : sigm(acc1[i][j][r]);
        pkt[r] = f2bf(v);
      }
      *reinterpret_cast<ushort4v*>(dst + (size_t)e * MROWS + mrow) = pkt;
    }
  }
}

__global__ __launch_bounds__(256, 4) void proj_kernel(
    const unsigned short* __restrict__ x,    // [M][128] bf16
    const unsigned short* __restrict__ wT,   // 6 x [128][128] bf16 [n][k]
    unsigned short* __restrict__ leftT,
    unsigned short* __restrict__ rightT,
    unsigned short* __restrict__ gateT) {
  __shared__ char xs[16384];                 // 64 rows x 256B, swizzled
  const int tid = threadIdx.x;
  const int m0 = blockIdx.x * 64;
  #pragma unroll
  for (int i = 0; i < 4; ++i) {
    int c = i * 256 + tid;
    int r = c >> 4, cb = (c & 15) << 4;
    *reinterpret_cast<short8*>(xs + SWZ(r, cb)) =
      *reinterpret_cast<const short8*>(x + (size_t)(m0 + r) * ZD + (cb >> 1));
  }
  __syncthreads();
  const int wid = tid >> 6, lane = tid & 63;
  const int msub = (wid >> 1) * 32, esub = (wid & 1) * 64;
  const int fr = lane & 15, fq = lane >> 4;
  proj_job<true >(xs, wT,               wT + ZD * ZD,     leftT,  m0, msub, esub, fr, fq);
  proj_job<true >(xs, wT + 2 * ZD * ZD, wT + 3 * ZD * ZD, rightT, m0, msub, esub, fr, fq);
  proj_job<false>(xs, wT + 4 * ZD * ZD, nullptr,          gateT,  m0, msub, esub, fr, fq);
}

// ---------------------------------------------------------------- einsum: per-channel GEMM-BT, 256^2 tile
// pT[e][s][t] = sum_r leftT[e][s][r] * rightT[e][t][r]
__global__ __launch_bounds__(512) void einsum_kernel(
    const unsigned short* __restrict__ leftT,
    const unsigned short* __restrict__ rightT,
    unsigned short* __restrict__ pT) {
  __shared__ char lds[131072];   // A0(32K) B0(32K) A1(32K) B1(32K)
  const int tid = threadIdx.x;
  const int e = blockIdx.z;
  const int t0 = blockIdx.x * 256, s0 = blockIdx.y * 256;
  const unsigned short* Ag = rightT + (size_t)e * MROWS;   // rows = t
  const unsigned short* Bg = leftT  + (size_t)e * MROWS;   // rows = s
  const int wid = tid >> 6, lane = tid & 63;
  const int tsub = (wid >> 2) * 128, ssub = (wid & 3) * 64;
  const int fr = lane & 15, fq = lane >> 4;
  floatx4 acc[8][4] = {};
  short8 stA[4], stB[4];

  #define EINS_LOAD(KO)                                                        \
    _Pragma("unroll")                                                          \
    for (int i2 = 0; i2 < 4; ++i2) {                                           \
      int c = i2 * 512 + tid;                                                  \
      int r = c >> 3, cs = (c & 7) << 3;                                       \
      stA[i2] = *reinterpret_cast<const short8*>(Ag + (size_t)(t0 + r) * SD + (KO) * 64 + cs); \
      stB[i2] = *reinterpret_cast<const short8*>(Bg + (size_t)(s0 + r) * SD + (KO) * 64 + cs); \
    }
  #define EINS_WRITE(BUF)                                                      \
    _Pragma("unroll")                                                          \
    for (int i2 = 0; i2 < 4; ++i2) {                                           \
      int c = i2 * 512 + tid;                                                  \
      int r = c >> 3, cb = (c & 7) << 4;                                       \
      *reinterpret_cast<short8*>(lds + (BUF) * 65536 + SWZ64(r, cb)) = stA[i2];\
      *reinterpret_cast<short8*>(lds + (BUF) * 65536 + 32768 + SWZ64(r, cb)) = stB[i2]; \
    }

  EINS_LOAD(0);
  EINS_WRITE(0);
  for (int ko = 0; ko < 8; ++ko) {
    const int cur = ko & 1;
    if (ko < 7) EINS_LOAD(ko + 1);
    __syncthreads();
    const char* Ab = lds + cur * 65536;
    const char* Bb = Ab + 32768;
    #pragma unroll
    for (int kk = 0; kk < 2; ++kk) {
      const int kb = kk * 64 + fq * 16;
      short8 a[8], b[4];
      #pragma unroll
      for (int i = 0; i < 8; ++i)
        a[i] = *reinterpret_cast<const short8*>(Ab + SWZ64(tsub + i * 16 + fr, kb));
      #pragma unroll
      for (int j = 0; j < 4; ++j)
        b[j] = *reinterpret_cast<const short8*>(Bb + SWZ64(ssub + j * 16 + fr, kb));
      #pragma unroll
      for (int i = 0; i < 8; ++i)
        #pragma unroll
        for (int j = 0; j < 4; ++j)
          acc[i][j] = __builtin_amdgcn_mfma_f32_16x16x32_bf16(a[i], b[j], acc[i][j], 0, 0, 0);
    }
    if (ko < 7) EINS_WRITE(cur ^ 1);
  }
  unsigned short* Pg = pT + (size_t)e * MROWS;
  #pragma unroll
  for (int i = 0; i < 8; ++i) {
    const int tt = t0 + tsub + i * 16 + fq * 4;       // 4 reg-consecutive t
    #pragma unroll
    for (int j = 0; j < 4; ++j) {
      const int ss = s0 + ssub + j * 16 + fr;
      ushort4v pkt;
      #pragma unroll
      for (int r = 0; r < 4; ++r) pkt[r] = f2bf(acc[i][j][r]);
      *reinterpret_cast<ushort4v*>(Pg + (size_t)ss * SD + tt) = pkt;
    }
  }
}

// ---------------------------------------------------------------- final: LN(E) + @out_w * gate + residual
__global__ __launch_bounds__(256) void final_kernel(
    const unsigned short* __restrict__ pT,     // [128][M]
    const unsigned short* __restrict__ gateT,  // [128][M]
    const unsigned short* __restrict__ owT,    // [z][e] bf16
    const float* __restrict__ nw, const float* __restrict__ nb,
    const float* __restrict__ resid, float* __restrict__ out) {
  __shared__ char Pn[128 * 256];   // [t][e] bf16 swizzled
  __shared__ char Gl[128 * 256];   // [z][t] bf16 swizzled
  __shared__ float red[512];
  __shared__ float mu_s[128], rs_s[128], nw_s[128], nb_s[128];
  const int tid = threadIdx.x;
  const int m0 = blockIdx.x * 128;
  // stage gate tile (swizzled)
  #pragma unroll
  for (int i = 0; i < 8; ++i) {
    int c = i * 256 + tid;
    int r = c >> 4, cb = (c & 15) << 4;
    *reinterpret_cast<short8*>(Gl + SWZ(r, cb)) =
      *reinterpret_cast<const short8*>(gateT + (size_t)r * MROWS + m0 + (cb >> 1));
  }
  if (tid < 128) { nw_s[tid] = nw[tid]; nb_s[tid] = nb[tid]; }
  const int t = tid & 127, h = tid >> 7;
  // LN pass 1: sums over e (coalesced global reads of pT columns)
  {
    float s = 0.f, q = 0.f;
    for (int e2 = 0; e2 < 64; ++e2) {
      float v = bf2f(pT[(size_t)(h * 64 + e2) * MROWS + m0 + t]);
      s += v; q += v * v;
    }
    red[h * 128 + t] = s;
    red[256 + h * 128 + t] = q;
  }
  __syncthreads();
  if (tid < 128) {
    float ss = red[tid] + red[128 + tid];
    float qq = red[256 + tid] + red[384 + tid];
    float mu = ss * (1.f / 128.f);
    float var = qq * (1.f / 128.f) - mu * mu;
    mu_s[tid] = mu;
    rs_s[tid] = rsqrtf(var + 1e-5f);
  }
  __syncthreads();
  // LN pass 2: normalize (re-read from L2), write swizzled Pn
  {
    float mu = mu_s[t], rs = rs_s[t];
    for (int e2 = 0; e2 < 64; ++e2) {
      int e = h * 64 + e2;
      float v = (bf2f(pT[(size_t)e * MROWS + m0 + t]) - mu) * rs * nw_s[e] + nb_s[e];
      *reinterpret_cast<unsigned short*>(Pn + SWZ(t, e * 2)) = f2bf(v);
    }
  }
  __syncthreads();
  const int wid = tid >> 6, lane = tid & 63;
  const int zsub = (wid >> 1) * 64, tsub = (wid & 1) * 64;
  const int fr = lane & 15, fq = lane >> 4;
  floatx4 acc[4][4] = {};
  #pragma unroll
  for (int ks = 0; ks < 4; ++ks) {
    short8 a[4], b[4];
    #pragma unroll
    for (int i = 0; i < 4; ++i)
      a[i] = *reinterpret_cast<const short8*>(owT + (size_t)(zsub + i * 16 + fr) * ZD + ks * 32 + fq * 8);
    #pragma unroll
    for (int j = 0; j < 4; ++j)
      b[j] = *reinterpret_cast<const short8*>(Pn + SWZ(tsub + j * 16 + fr, ks * 64 + fq * 16));
    #pragma unroll
    for (int i = 0; i < 4; ++i)
      #pragma unroll
      for (int j = 0; j < 4; ++j)
        acc[i][j] = __builtin_amdgcn_mfma_f32_16x16x32_bf16(a[i], b[j], acc[i][j], 0, 0, 0);
  }
  #pragma unroll
  for (int j = 0; j < 4; ++j) {
    const int tt = tsub + j * 16 + fr;
    #pragma unroll
    for (int i = 0; i < 4; ++i) {
      const int zb = zsub + i * 16 + fq * 4;          // 4 reg-consecutive z
      const float4 res = *reinterpret_cast<const float4*>(resid + (size_t)(m0 + tt) * ZD + zb);
      float g0 = bf2f(*reinterpret_cast<const unsigned short*>(Gl + SWZ(zb + 0, tt * 2)));
      float g1 = bf2f(*reinterpret_cast<const unsigned short*>(Gl + SWZ(zb + 1, tt * 2)));
      float g2 = bf2f(*reinterpret_cast<const unsigned short*>(Gl + SWZ(zb + 2, tt * 2)));
      float g3 = bf2f(*reinterpret_cast<const unsigned short*>(Gl + SWZ(zb + 3, tt * 2)));
      float4 o;
      o.x = res.x + acc[i][j][0] * g0;
      o.y = res.y + acc[i][j][1] * g1;
      o.z = res.z + acc[i][j][2] * g2;
      o.w = res.w + acc[i][j][3] * g3;
      *reinterpret_cast<float4*>(out + (size_t)(m0 + tt) * ZD + zb) = o;
    }
  }
}

// ----------------------------------------------------------------
extern "C" void kernel_launch(void* const* d_in, const int* in_sizes, int n_in,
                              void* d_out, int out_size, void* d_ws, size_t ws_size,
                              hipStream_t stream) {
  const float* pair = (const float*)d_in[0];
  const float* ln_w = (const float*)d_in[1];
  const float* ln_b = (const float*)d_in[2];
  const float* l1   = (const float*)d_in[3];
  const float* l2   = (const float*)d_in[4];
  const float* r1   = (const float*)d_in[5];
  const float* r2   = (const float*)d_in[6];
  const float* nw   = (const float*)d_in[7];
  const float* nb   = (const float*)d_in[8];
  const float* ow   = (const float*)d_in[9];
  const float* gw   = (const float*)d_in[10];
  float* out = (float*)d_out;

  unsigned short* xws   = reinterpret_cast<unsigned short*>(d_ws);
  unsigned short* gateT = xws + (size_t)MROWS * ZD;
  unsigned short* wT    = gateT + (size_t)MROWS * ZD;
  unsigned short* owT   = wT + (size_t)5 * ZD * ZD;
  unsigned short* leftT  = reinterpret_cast<unsigned short*>(d_out);   // dead before final
  unsigned short* rightT = leftT + (size_t)MROWS * ZD;
  unsigned short* pTbuf  = xws;   // alias x (x dead after proj_kernel)

  prep_weights<<<6, 256, 0, stream>>>(l1, l2, r1, r2, gw, ow, wT);
  ln_kernel<<<MROWS / 4, 256, 0, stream>>>(pair, ln_w, ln_b, xws);
  proj_kernel<<<4096, 256, 0, stream>>>(xws, wT, leftT, rightT, gateT);
  einsum_kernel<<<dim3(2, 2, 128), 512, 0, stream>>>(leftT, rightT, pTbuf);
  final_kernel<<<2048, 256, 0, stream>>>(pTbuf, gateT, owT, nw, nb, pair, out);
}

// Round 5
// 518.599 us; speedup vs baseline: 1.3488x; 1.3488x over previous
//
#include <hip/hip_runtime.h>
#include <hip/hip_bf16.h>
#include <stdint.h>

#define ZD 128
#define SD 512
#define MROWS (SD*SD)   // 262144 rows
#define PTILES 8

typedef __attribute__((ext_vector_type(8))) short short8;
typedef __attribute__((ext_vector_type(4))) float floatx4;
typedef __attribute__((ext_vector_type(4))) unsigned short ushort4v;

__device__ __forceinline__ unsigned short f2bf(float f) {
  __hip_bfloat16 h = __float2bfloat16(f);   // RNE, compiler can pack via v_cvt_pk_bf16_f32
  return reinterpret_cast<unsigned short&>(h);
}
__device__ __forceinline__ float bf2f(unsigned short h) {
  union { unsigned u; float f; } c; c.u = (unsigned)h << 16;
  return c.f;
}
__device__ __forceinline__ float sigm(float x) { return 1.0f / (1.0f + __expf(-x)); }

// swizzled LDS byte offset for 256B rows
#define SWZ(r, cb) (((r) << 8) + ((cb) ^ (((r) & 7) << 4)))
// swizzled LDS byte offset for 128B rows
#define SWZ64(r, cb) (((r) << 7) + ((cb) ^ (((r) & 7) << 4)))

// ---------------------------------------------------------------- prep: bf16+transpose weights
__global__ __launch_bounds__(256) void prep_weights(
    const float* __restrict__ l1, const float* __restrict__ l2,
    const float* __restrict__ r1, const float* __restrict__ r2,
    const float* __restrict__ gw, const float* __restrict__ ow,
    unsigned short* __restrict__ dst) {
  const float* srcs[6] = {l1, l2, r1, r2, gw, ow};
  const float* s = srcs[blockIdx.x];
  unsigned short* d = dst + (size_t)blockIdx.x * ZD * ZD;
  for (int i = threadIdx.x; i < ZD * ZD; i += blockDim.x) {
    int k = i >> 7, n = i & 127;
    d[n * ZD + k] = f2bf(s[i]);     // WT[n][k] = W[k][n]
  }
}

// ---------------------------------------------------------------- LN over Z, f32 -> bf16 x
__global__ __launch_bounds__(256) void ln_kernel(
    const float* __restrict__ in, const float* __restrict__ w,
    const float* __restrict__ b, unsigned short* __restrict__ xo) {
  const int tid = threadIdx.x;
  const int lane = tid & 63;
  const int row = blockIdx.x * 4 + (tid >> 6);
  float2 v = reinterpret_cast<const float2*>(in)[(size_t)row * 64 + lane];
  float s = v.x + v.y, q = v.x * v.x + v.y * v.y;
  #pragma unroll
  for (int m = 1; m < 64; m <<= 1) { s += __shfl_xor(s, m); q += __shfl_xor(q, m); }
  float mu = s * (1.0f / ZD);
  float var = q * (1.0f / ZD) - mu * mu;
  float rstd = rsqrtf(var + 1e-5f);
  float2 wv = reinterpret_cast<const float2*>(w)[lane];
  float2 bv = reinterpret_cast<const float2*>(b)[lane];
  unsigned o0 = f2bf((v.x - mu) * rstd * wv.x + bv.x);
  unsigned o1 = f2bf((v.y - mu) * rstd * wv.y + bv.y);
  reinterpret_cast<unsigned*>(xo)[(size_t)row * 64 + lane] = o0 | (o1 << 16);
}

// ---------------------------------------------------------------- projections: persistent-weight GEMM
// blockIdx.y: 0 -> leftT = sig(x@l1)*(x@l2); 1 -> rightT = sig(x@r1)*(x@r2)
// each block: 8 m-tiles of 64 rows; weights live in registers; stores bounce
// through LDS so each global store instruction covers full 64B lines.
__global__ __launch_bounds__(256) void proj_kernel(
    const unsigned short* __restrict__ x,    // [M][128] bf16
    const unsigned short* __restrict__ wT,   // 6 x [128][128] bf16 [n][k]
    unsigned short* __restrict__ leftT,
    unsigned short* __restrict__ rightT) {
  __shared__ char xs[16384];          // 64 rows x 256B, swizzled
  __shared__ char bn[128 * 160];      // bounce: 128 e-rows x 128B data (160B stride)
  const int tid = threadIdx.x;
  const int wid = tid >> 6, lane = tid & 63;
  const int fr = lane & 15, fq = lane >> 4;
  const int esub = (wid & 3) * 32;    // each wave owns a 32-wide e-slice
  const int job = blockIdx.y;
  const unsigned short* w1 = wT + (size_t)(job * 2) * ZD * ZD;
  const unsigned short* w2 = w1 + ZD * ZD;
  unsigned short* dst = job ? rightT : leftT;

  // persistent weight fragments: 2 matrices x (j=2, ks=4) x short8 = 64 VGPR
  short8 wf1[2][4], wf2[2][4];
  #pragma unroll
  for (int j = 0; j < 2; ++j)
    #pragma unroll
    for (int ks = 0; ks < 4; ++ks) {
      const int erow = esub + j * 16 + fr;
      wf1[j][ks] = *reinterpret_cast<const short8*>(w1 + erow * ZD + ks * 32 + fq * 8);
      wf2[j][ks] = *reinterpret_cast<const short8*>(w2 + erow * ZD + ks * 32 + fq * 8);
    }

  const int m0 = blockIdx.x * (PTILES * 64);
  short8 xr[4];
  #pragma unroll
  for (int i = 0; i < 4; ++i) {
    int c = i * 256 + tid;
    xr[i] = *reinterpret_cast<const short8*>(x + (size_t)(m0 + (c >> 4)) * ZD + ((c & 15) << 3));
  }

  for (int it = 0; it < PTILES; ++it) {
    const int mt = m0 + it * 64;
    #pragma unroll
    for (int i = 0; i < 4; ++i) {
      int c = i * 256 + tid;
      *reinterpret_cast<short8*>(xs + SWZ(c >> 4, (c & 15) << 4)) = xr[i];
    }
    __syncthreads();
    if (it < PTILES - 1) {                      // T14: issue next-tile loads early
      #pragma unroll
      for (int i = 0; i < 4; ++i) {
        int c = i * 256 + tid;
        xr[i] = *reinterpret_cast<const short8*>(x + (size_t)(mt + 64 + (c >> 4)) * ZD + ((c & 15) << 3));
      }
    }
    floatx4 acc1[4][2] = {}, acc2[4][2] = {};
    #pragma unroll
    for (int ks = 0; ks < 4; ++ks) {
      const int kb = ks * 64 + fq * 16;
      short8 a[4];
      #pragma unroll
      for (int i = 0; i < 4; ++i)
        a[i] = *reinterpret_cast<const short8*>(xs + SWZ(i * 16 + fr, kb));
      #pragma unroll
      for (int i = 0; i < 4; ++i)
        #pragma unroll
        for (int j = 0; j < 2; ++j) {
          acc1[i][j] = __builtin_amdgcn_mfma_f32_16x16x32_bf16(a[i], wf1[j][ks], acc1[i][j], 0, 0, 0);
          acc2[i][j] = __builtin_amdgcn_mfma_f32_16x16x32_bf16(a[i], wf2[j][ks], acc2[i][j], 0, 0, 0);
        }
    }
    // combine + write to bounce (XOR-swizzled within 128B row, 160B row stride)
    #pragma unroll
    for (int i = 0; i < 4; ++i)
      #pragma unroll
      for (int j = 0; j < 2; ++j) {
        const int el = esub + j * 16 + fr;
        const int mb = i * 32 + fq * 8;          // byte offset of 4 m-values
        ushort4v p;
        #pragma unroll
        for (int r = 0; r < 4; ++r)
          p[r] = f2bf(sigm(acc1[i][j][r]) * acc2[i][j][r]);
        *reinterpret_cast<ushort4v*>(bn + el * 160 + (mb ^ ((el & 7) << 4))) = p;
      }
    __syncthreads();
    // coalesced stores: each instruction covers 8 full e-rows (full 64B lines)
    #pragma unroll
    for (int q = 0; q < 4; ++q) {
      int c = q * 256 + tid;                     // 1024 chunks of 16B
      int e = c >> 3, mq = (c & 7) << 4;
      short8 v = *reinterpret_cast<const short8*>(bn + e * 160 + (mq ^ ((e & 7) << 4)));
      *reinterpret_cast<short8*>(dst + (size_t)e * MROWS + mt + (mq >> 1)) = v;
    }
    __syncthreads();
  }
}

// ---------------------------------------------------------------- einsum: per-channel GEMM-BT, 256^2 tile
// pT[e][s][t] = sum_r leftT[e][s][r] * rightT[e][t][r]
__global__ __launch_bounds__(512) void einsum_kernel(
    const unsigned short* __restrict__ leftT,
    const unsigned short* __restrict__ rightT,
    unsigned short* __restrict__ pT) {
  __shared__ char lds[131072];   // A0(32K) B0(32K) A1(32K) B1(32K)
  const int tid = threadIdx.x;
  const int e = blockIdx.z;
  const int t0 = blockIdx.x * 256, s0 = blockIdx.y * 256;
  const unsigned short* Ag = rightT + (size_t)e * MROWS;   // rows = t
  const unsigned short* Bg = leftT  + (size_t)e * MROWS;   // rows = s
  const int wid = tid >> 6, lane = tid & 63;
  const int tsub = (wid >> 2) * 128, ssub = (wid & 3) * 64;
  const int fr = lane & 15, fq = lane >> 4;
  floatx4 acc[8][4] = {};
  short8 stA[4], stB[4];

  #define EINS_LOAD(KO)                                                        \
    _Pragma("unroll")                                                          \
    for (int i2 = 0; i2 < 4; ++i2) {                                           \
      int c = i2 * 512 + tid;                                                  \
      int r = c >> 3, cs = (c & 7) << 3;                                       \
      stA[i2] = *reinterpret_cast<const short8*>(Ag + (size_t)(t0 + r) * SD + (KO) * 64 + cs); \
      stB[i2] = *reinterpret_cast<const short8*>(Bg + (size_t)(s0 + r) * SD + (KO) * 64 + cs); \
    }
  #define EINS_WRITE(BUF)                                                      \
    _Pragma("unroll")                                                          \
    for (int i2 = 0; i2 < 4; ++i2) {                                           \
      int c = i2 * 512 + tid;                                                  \
      int r = c >> 3, cb = (c & 7) << 4;                                       \
      *reinterpret_cast<short8*>(lds + (BUF) * 65536 + SWZ64(r, cb)) = stA[i2];\
      *reinterpret_cast<short8*>(lds + (BUF) * 65536 + 32768 + SWZ64(r, cb)) = stB[i2]; \
    }

  EINS_LOAD(0);
  EINS_WRITE(0);
  for (int ko = 0; ko < 8; ++ko) {
    const int cur = ko & 1;
    if (ko < 7) EINS_LOAD(ko + 1);
    __syncthreads();
    const char* Ab = lds + cur * 65536;
    const char* Bb = Ab + 32768;
    #pragma unroll
    for (int kk = 0; kk < 2; ++kk) {
      const int kb = kk * 64 + fq * 16;
      short8 a[8], b[4];
      #pragma unroll
      for (int i = 0; i < 8; ++i)
        a[i] = *reinterpret_cast<const short8*>(Ab + SWZ64(tsub + i * 16 + fr, kb));
      #pragma unroll
      for (int j = 0; j < 4; ++j)
        b[j] = *reinterpret_cast<const short8*>(Bb + SWZ64(ssub + j * 16 + fr, kb));
      #pragma unroll
      for (int i = 0; i < 8; ++i)
        #pragma unroll
        for (int j = 0; j < 4; ++j)
          acc[i][j] = __builtin_amdgcn_mfma_f32_16x16x32_bf16(a[i], b[j], acc[i][j], 0, 0, 0);
    }
    if (ko < 7) EINS_WRITE(cur ^ 1);
  }
  unsigned short* Pg = pT + (size_t)e * MROWS;
  #pragma unroll
  for (int i = 0; i < 8; ++i) {
    const int tt = t0 + tsub + i * 16 + fq * 4;       // 4 reg-consecutive t
    #pragma unroll
    for (int j = 0; j < 4; ++j) {
      const int ss = s0 + ssub + j * 16 + fr;
      ushort4v pkt;
      #pragma unroll
      for (int r = 0; r < 4; ++r) pkt[r] = f2bf(acc[i][j][r]);
      *reinterpret_cast<ushort4v*>(Pg + (size_t)ss * SD + tt) = pkt;
    }
  }
}

// ---------------------------------------------------------------- final: LN(E) + @out_w, gate computed in-kernel
__global__ __launch_bounds__(256) void final_kernel(
    const unsigned short* __restrict__ pT,     // [128][M]
    const unsigned short* __restrict__ x,      // [M][128] bf16 (LN'd input)
    const unsigned short* __restrict__ gwT,    // [z][k] bf16
    const unsigned short* __restrict__ owT,    // [z][e] bf16
    const float* __restrict__ nw, const float* __restrict__ nb,
    const float* __restrict__ resid, float* __restrict__ out) {
  __shared__ char Pn[128 * 256];   // [t][e] bf16 swizzled
  __shared__ char Xs[128 * 256];   // [t][k] bf16 swizzled
  __shared__ float red[512];
  __shared__ float mu_s[128], rs_s[128], nw_s[128], nb_s[128];
  const int tid = threadIdx.x;
  const int m0 = blockIdx.x * 128;
  // stage x tile (swizzled) for the gate GEMM
  #pragma unroll
  for (int i = 0; i < 8; ++i) {
    int c = i * 256 + tid;
    int r = c >> 4, cb = (c & 15) << 4;
    *reinterpret_cast<short8*>(Xs + SWZ(r, cb)) =
      *reinterpret_cast<const short8*>(x + (size_t)(m0 + r) * ZD + (cb >> 1));
  }
  if (tid < 128) { nw_s[tid] = nw[tid]; nb_s[tid] = nb[tid]; }
  __syncthreads();
  const int wid = tid >> 6, lane = tid & 63;
  const int zsub = (wid >> 1) * 64, tsub = (wid & 1) * 64;
  const int fr = lane & 15, fq = lane >> 4;
  // gate GEMM: D[z][t] = sum_k gwT[z][k] * x[t][k]
  floatx4 accg[4][4] = {};
  #pragma unroll
  for (int ks = 0; ks < 4; ++ks) {
    short8 a[4], b[4];
    #pragma unroll
    for (int i = 0; i < 4; ++i)
      a[i] = *reinterpret_cast<const short8*>(gwT + (size_t)(zsub + i * 16 + fr) * ZD + ks * 32 + fq * 8);
    #pragma unroll
    for (int j = 0; j < 4; ++j)
      b[j] = *reinterpret_cast<const short8*>(Xs + SWZ(tsub + j * 16 + fr, ks * 64 + fq * 16));
    #pragma unroll
    for (int i = 0; i < 4; ++i)
      #pragma unroll
      for (int j = 0; j < 4; ++j)
        accg[i][j] = __builtin_amdgcn_mfma_f32_16x16x32_bf16(a[i], b[j], accg[i][j], 0, 0, 0);
  }
  const int t = tid & 127, h = tid >> 7;
  // LN pass 1: sums over e (coalesced global reads of pT columns)
  {
    float s = 0.f, q = 0.f;
    for (int e2 = 0; e2 < 64; ++e2) {
      float v = bf2f(pT[(size_t)(h * 64 + e2) * MROWS + m0 + t]);
      s += v; q += v * v;
    }
    red[h * 128 + t] = s;
    red[256 + h * 128 + t] = q;
  }
  __syncthreads();
  if (tid < 128) {
    float ss = red[tid] + red[128 + tid];
    float qq = red[256 + tid] + red[384 + tid];
    float mu = ss * (1.f / 128.f);
    float var = qq * (1.f / 128.f) - mu * mu;
    mu_s[tid] = mu;
    rs_s[tid] = rsqrtf(var + 1e-5f);
  }
  __syncthreads();
  // LN pass 2: normalize (re-read from L2), write swizzled Pn
  {
    float mu = mu_s[t], rs = rs_s[t];
    for (int e2 = 0; e2 < 64; ++e2) {
      int e = h * 64 + e2;
      float v = (bf2f(pT[(size_t)e * MROWS + m0 + t]) - mu) * rs * nw_s[e] + nb_s[e];
      *reinterpret_cast<unsigned short*>(Pn + SWZ(t, e * 2)) = f2bf(v);
    }
  }
  __syncthreads();
  floatx4 acc[4][4] = {};
  #pragma unroll
  for (int ks = 0; ks < 4; ++ks) {
    short8 a[4], b[4];
    #pragma unroll
    for (int i = 0; i < 4; ++i)
      a[i] = *reinterpret_cast<const short8*>(owT + (size_t)(zsub + i * 16 + fr) * ZD + ks * 32 + fq * 8);
    #pragma unroll
    for (int j = 0; j < 4; ++j)
      b[j] = *reinterpret_cast<const short8*>(Pn + SWZ(tsub + j * 16 + fr, ks * 64 + fq * 16));
    #pragma unroll
    for (int i = 0; i < 4; ++i)
      #pragma unroll
      for (int j = 0; j < 4; ++j)
        acc[i][j] = __builtin_amdgcn_mfma_f32_16x16x32_bf16(a[i], b[j], acc[i][j], 0, 0, 0);
  }
  #pragma unroll
  for (int j = 0; j < 4; ++j) {
    const int tt = tsub + j * 16 + fr;
    #pragma unroll
    for (int i = 0; i < 4; ++i) {
      const int zb = zsub + i * 16 + fq * 4;          // 4 reg-consecutive z
      const float4 res = *reinterpret_cast<const float4*>(resid + (size_t)(m0 + tt) * ZD + zb);
      float4 o;
      o.x = res.x + acc[i][j][0] * sigm(accg[i][j][0]);
      o.y = res.y + acc[i][j][1] * sigm(accg[i][j][1]);
      o.z = res.z + acc[i][j][2] * sigm(accg[i][j][2]);
      o.w = res.w + acc[i][j][3] * sigm(accg[i][j][3]);
      *reinterpret_cast<float4*>(out + (size_t)(m0 + tt) * ZD + zb) = o;
    }
  }
}

// ----------------------------------------------------------------
extern "C" void kernel_launch(void* const* d_in, const int* in_sizes, int n_in,
                              void* d_out, int out_size, void* d_ws, size_t ws_size,
                              hipStream_t stream) {
  const float* pair = (const float*)d_in[0];
  const float* ln_w = (const float*)d_in[1];
  const float* ln_b = (const float*)d_in[2];
  const float* l1   = (const float*)d_in[3];
  const float* l2   = (const float*)d_in[4];
  const float* r1   = (const float*)d_in[5];
  const float* r2   = (const float*)d_in[6];
  const float* nw   = (const float*)d_in[7];
  const float* nb   = (const float*)d_in[8];
  const float* ow   = (const float*)d_in[9];
  const float* gw   = (const float*)d_in[10];
  float* out = (float*)d_out;

  // ws layout (bf16 elems): x [0,33.5M) | pT [33.5M,67M) | weights
  unsigned short* xws   = reinterpret_cast<unsigned short*>(d_ws);
  unsigned short* pTbuf = xws + (size_t)MROWS * ZD;
  unsigned short* wT    = pTbuf + (size_t)MROWS * ZD;
  unsigned short* gwT   = wT + (size_t)4 * ZD * ZD;
  unsigned short* owT   = wT + (size_t)5 * ZD * ZD;
  unsigned short* leftT  = reinterpret_cast<unsigned short*>(d_out);   // dead before final's writes
  unsigned short* rightT = leftT + (size_t)MROWS * ZD;

  prep_weights<<<6, 256, 0, stream>>>(l1, l2, r1, r2, gw, ow, wT);
  ln_kernel<<<MROWS / 4, 256, 0, stream>>>(pair, ln_w, ln_b, xws);
  proj_kernel<<<dim3(512, 2), 256, 0, stream>>>(xws, wT, leftT, rightT);
  einsum_kernel<<<dim3(2, 2, 128), 512, 0, stream>>>(leftT, rightT, pTbuf);
  final_kernel<<<2048, 256, 0, stream>>>(pTbuf, xws, gwT, owT, nw, nb, pair, out);
}